// Round 8
// baseline (3616.955 us; speedup 1.0000x reference)
//
#include <hip/hip_runtime.h>

typedef short s8v __attribute__((ext_vector_type(8)));
typedef float f32x4 __attribute__((ext_vector_type(4)));

#define OBS_T 8
#define NSTEPS 20

__device__ __forceinline__ unsigned short f2bf(float x) {
    unsigned u = __float_as_uint(x);
    u = (u + 0x7FFFu + ((u >> 16) & 1u)) >> 16;
    return (unsigned short)u;
}
__device__ __forceinline__ float bf2f(unsigned short h) {
    return __uint_as_float(((unsigned)h) << 16);
}

__device__ __forceinline__ void store2(unsigned short* H, unsigned short* M,
                                       int ci, float v) {
    unsigned short h = f2bf(v);
    H[ci] = h; M[ci] = f2bf(v - bf2f(h));
}

// ---------------- prep: pack x2-split bf16 weight fragments (unchanged) ----------------
__global__ void slstm_prep(const float* __restrict__ Wp,
                           const float* __restrict__ Wi, const float* __restrict__ Wf,
                           const float* __restrict__ Wo, const float* __restrict__ Wg,
                           unsigned short* __restrict__ W4H, unsigned short* __restrict__ W4L,
                           unsigned short* __restrict__ WpH, unsigned short* __restrict__ WpL) {
    int x = blockIdx.x * blockDim.x + threadIdx.x;
    const int NW4 = 32 * 8 * 64 * 8;      // 131072
    const int NWP = 64 * 4 * 4 * 64 * 8;  // 524288
    if (x < NW4) {
        int j = x & 7, lane = (x >> 3) & 63, ks = (x >> 9) & 7, nt2 = x >> 12;
        int q = nt2 & 3, wvb = nt2 >> 2;
        int col = wvb * 16 + (lane & 15);
        int k = ks * 32 + ((lane >> 4) << 3) + j;
        const float* W = (q == 0) ? Wi : (q == 1) ? Wf : (q == 2) ? Wo : Wg;
        float v = W[k * 128 + col];
        unsigned short h = f2bf(v);
        W4H[x] = h; W4L[x] = f2bf(v - bf2f(h));
    } else if (x < NW4 + NWP) {
        int y = x - NW4;
        int j = y & 7, lane = (y >> 3) & 63, ks = (y >> 9) & 3, nt = (y >> 11) & 3, bin = y >> 13;
        int e = nt * 16 + (lane & 15);
        int k = ks * 32 + ((lane >> 4) << 3) + j;
        float v = Wp[(bin * 128 + k) * 64 + e];
        unsigned short h = f2bf(v);
        WpH[y] = h; WpL[y] = f2bf(v - bf2f(h));
    }
}

#define LOAD_PAIR(buf, bin, pairBase)                                      \
    {                                                                      \
        for (int kk = 0; kk < 4; ++kk) {                                   \
            int foA = (((bin) * 4 + (pairBase)) * 4 + kk) * 64 + lane;     \
            int foB = (((bin) * 4 + (pairBase) + 1) * 4 + kk) * 64 + lane; \
            pbh[buf][0][kk] = ((const s8v*)WpH)[foA];                      \
            pbl[buf][0][kk] = ((const s8v*)WpL)[foA];                      \
            pbh[buf][1][kk] = ((const s8v*)WpH)[foB];                      \
            pbl[buf][1][kk] = ((const s8v*)WpL)[foB];                      \
        }                                                                  \
    }

// ---------------- main persistent kernel: 1 WG (1024 thr, 16 waves) per sequence ----------------
__global__ __launch_bounds__(1024, 1) void slstm_main(
    const float* __restrict__ obs_rel, const float* __restrict__ obs_abs,
    const float* __restrict__ We, const float* __restrict__ be,
    const float* __restrict__ bp,
    const float* __restrict__ bi, const float* __restrict__ bfv,
    const float* __restrict__ bo, const float* __restrict__ bg,
    const float* __restrict__ Wout, const float* __restrict__ bout,
    const unsigned short* __restrict__ W4H, const unsigned short* __restrict__ W4L,
    const unsigned short* __restrict__ WpH, const unsigned short* __restrict__ WpL,
    float* __restrict__ out) {

    __shared__ __align__(16) unsigned short combH[32 * 256];
    __shared__ __align__(16) unsigned short combM[32 * 256];
    __shared__ __align__(16) float hbuf[32 * 128];
    __shared__ __align__(16) float scratch[32 * 512];
    __shared__ float posb[64];
    __shared__ float pvbuf[64];
    __shared__ float red[256];
    __shared__ unsigned char binTab[1024];
    __shared__ unsigned char usedList[64];
    __shared__ unsigned char binSlotG[64];
    __shared__ unsigned short glist[1024];
    __shared__ unsigned long long gstartPacked[32];
    __shared__ int nUsedS;
    __shared__ unsigned usedMask[2];
    __shared__ unsigned jm[4];
    __shared__ float biasL[512], beL[64], bpL[64], WeL[128], WoutL[256], boutL[2];

    const int tid = threadIdx.x;
    const int lane = tid & 63;
    const int wv = tid >> 6;          // 0..15
    const int wv8 = wv & 7;           // bin slot / hcol block
    const int wvh = wv >> 3;          // j-half (social) / row-half (gates)
    const int b = blockIdx.x;

    if (tid < 512) biasL[tid] = (tid < 128) ? bi[tid] : (tid < 256) ? bfv[tid - 128]
                              : (tid < 384) ? bo[tid - 256] : bg[tid - 384];
    if (tid < 64) { beL[tid] = be[tid]; bpL[tid] = bp[tid]; }
    if (tid < 128) WeL[tid] = We[tid];
    if (tid < 256) WoutL[tid] = Wout[tid];
    if (tid < 2) boutL[tid] = bout[tid];
    for (int x = tid; x < 32 * 256; x += 1024) { combH[x] = 0; combM[x] = 0; }
    for (int x = tid; x < 32 * 128; x += 1024) hbuf[x] = 0.f;
    float creg[4];
#pragma unroll
    for (int r = 0; r < 4; ++r) creg[r] = 0.f;
    __syncthreads();

    const float gnorm = (float)(2.0 / 7.0);
    const int gi = tid >> 5;          // ped 0..31 (gather / emb / s-finalize)
    const int ge = (tid & 31) * 2;    // two e's per thread
    const int hc = wv8 * 16 + (lane & 15);        // gate/cell hcol
    const int arow = wvh * 16 + (lane & 15);      // A-frag row (own half)

    for (int t = 0; t < NSTEPS; ++t) {
        // ---------- E_obs ----------
        if (t < OBS_T) {
            if (tid < 64) posb[tid] = obs_abs[t * 2048 + b * 64 + tid];
            {
                float x0 = obs_rel[t * 2048 + b * 64 + gi * 2];
                float x1 = obs_rel[t * 2048 + b * 64 + gi * 2 + 1];
#pragma unroll
                for (int r = 0; r < 2; ++r) {
                    int e = ge + r;
                    float v = x0 * WeL[e] + x1 * WeL[64 + e] + beL[e];
                    store2(combH, combM, gi * 256 + (e ^ ((gi & 7) << 3)), v);
                }
            }
        }
        if (tid < 2) usedMask[tid] = 0u;
        if (tid < 4) jm[tid] = 0u;
        __syncthreads();

        // ---------- S0: bins (one pair per thread) ----------
        if (t > 0) {
            int i = tid >> 5, j = tid & 31;
            float rx = (posb[j * 2]     - posb[i * 2])     / gnorm;
            float ry = (posb[j * 2 + 1] - posb[i * 2 + 1]) / gnorm;
            rx = fminf(fmaxf(rx, -4.f), 4.f);
            ry = fminf(fmaxf(ry, -4.f), 4.f);
            int gx = (int)(rx + 4.f);
            int gy = (int)(ry + 4.f);
            int valid = (gx < 8) && (gy < 8) && (i != j);
            int bin = gy * 8 + gx;
            binTab[tid] = valid ? (unsigned char)bin : (unsigned char)255;
            if (valid) {
                atomicOr(&usedMask[bin >> 5], 1u << (bin & 31));
                atomicOr(&jm[((j < 16) ? 0 : 2) + (bin >> 5)], 1u << (bin & 31));
            }
        }
        __syncthreads();
        // ---------- S1: ballot compaction (wave 0) ----------
        if (t > 0 && wv == 0) {
            bool used = (usedMask[lane >> 5] >> (lane & 31)) & 1u;
            unsigned long long bal = __ballot(used);
            int myIdx = __popcll(bal & ((1ull << lane) - 1ull));
            if (used) usedList[myIdx] = (unsigned char)lane;
            binSlotG[lane] = used ? (unsigned char)myIdx : (unsigned char)255;
            if (lane == 0) nUsedS = __popcll(bal);
        }
        __syncthreads();
        const int nUsed = (t > 0) ? nUsedS : 0;
        const int nChunks = (nUsed + 7) >> 3;

        // A-frags for own row/j half (comb cols 64..191) — also reused by gates ks2..5
        s8v Ahs[4], Ams[4];
#pragma unroll
        for (int ks = 0; ks < 4; ++ks) {
            int k = ks * 32 + ((lane >> 4) << 3);
            int ci = arow * 256 + ((64 + k) ^ ((arow & 7) << 3));
            Ahs[ks] = *(const s8v*)&combH[ci];
            Ams[ks] = *(const s8v*)&combM[ci];
        }

        // glist build (tid<32)
        if (t > 0 && tid < 32) {
            const int i = tid;
            unsigned rw[8];
#pragma unroll
            for (int w = 0; w < 8; ++w)
                rw[w] = *(const unsigned*)&binTab[i * 32 + w * 4];
            unsigned long long cntp = 0;
#pragma unroll
            for (int j = 0; j < 32; ++j) {
                unsigned bb = (rw[j >> 2] >> ((j & 3) * 8)) & 255u;
                if (bb != 255u) cntp += 1ull << (5 * (binSlotG[bb] >> 3));
            }
            unsigned long long pre = 0; unsigned sum = 0;
#pragma unroll
            for (int c = 0; c < 8; ++c) {
                pre |= (unsigned long long)sum << (5 * c);
                sum += (unsigned)((cntp >> (5 * c)) & 31);
            }
            gstartPacked[i] = pre | ((unsigned long long)sum << 40);
            unsigned long long pos = pre;
#pragma unroll
            for (int j = 0; j < 32; ++j) {
                unsigned bb = (rw[j >> 2] >> ((j & 3) * 8)) & 255u;
                if (bb != 255u) {
                    int sg = binSlotG[bb];
                    int c = sg >> 3;
                    int p = (int)((pos >> (5 * c)) & 31);
                    glist[i * 32 + p] = (unsigned short)((sg << 5) | j);
                    pos += 1ull << (5 * c);
                }
            }
        }

        float sreg0 = 0.f, sreg1 = 0.f;
        if (t > 0) {
            s8v pbh[2][2][4], pbl[2][2][4];
            unsigned long long spReg = 0;
            bool act = false; int bin = 0;
            if (wv8 < nUsed) {
                bin = usedList[wv8];
                act = (jm[2 * wvh + (bin >> 5)] >> (bin & 31)) & 1;
            }
            if (act) LOAD_PAIR(0, bin, 0);

            for (int c = 0; c < nChunks; ++c) {
                bool nact = false; int nbin = 0;
                int idxn = (c + 1) * 8 + wv8;
                if (c + 1 < nChunks && idxn < nUsed) {
                    nbin = usedList[idxn];
                    nact = (jm[2 * wvh + (nbin >> 5)] >> (nbin & 31)) & 1;
                }
                if (act) {
                    LOAD_PAIR(1, bin, 2);   // pair1 of current chunk
                    f32x4 a0 = {0.f, 0.f, 0.f, 0.f};
                    f32x4 a1 = {0.f, 0.f, 0.f, 0.f};
#pragma unroll
                    for (int ks = 0; ks < 4; ++ks) {
                        a0 = __builtin_amdgcn_mfma_f32_16x16x32_bf16(Ams[ks], pbh[0][0][ks], a0, 0, 0, 0);
                        a0 = __builtin_amdgcn_mfma_f32_16x16x32_bf16(Ahs[ks], pbl[0][0][ks], a0, 0, 0, 0);
                        a0 = __builtin_amdgcn_mfma_f32_16x16x32_bf16(Ahs[ks], pbh[0][0][ks], a0, 0, 0, 0);
                        a1 = __builtin_amdgcn_mfma_f32_16x16x32_bf16(Ams[ks], pbh[0][1][ks], a1, 0, 0, 0);
                        a1 = __builtin_amdgcn_mfma_f32_16x16x32_bf16(Ahs[ks], pbl[0][1][ks], a1, 0, 0, 0);
                        a1 = __builtin_amdgcn_mfma_f32_16x16x32_bf16(Ahs[ks], pbh[0][1][ks], a1, 0, 0, 0);
                    }
#pragma unroll
                    for (int nt = 0; nt < 2; ++nt) {
                        int e = nt * 16 + (lane & 15);
                        const f32x4 a = nt ? a1 : a0;
#pragma unroll
                        for (int r = 0; r < 4; ++r) {
                            int j = wvh * 16 + ((lane >> 4) << 2) + r;
                            scratch[j * 512 + wv8 * 64 + (e ^ (((j >> 2) & 3) << 4))] = a[r];
                        }
                    }
                    if (nact) LOAD_PAIR(0, nbin, 0);   // next chunk pair0
                    f32x4 a2 = {0.f, 0.f, 0.f, 0.f};
                    f32x4 a3 = {0.f, 0.f, 0.f, 0.f};
#pragma unroll
                    for (int ks = 0; ks < 4; ++ks) {
                        a2 = __builtin_amdgcn_mfma_f32_16x16x32_bf16(Ams[ks], pbh[1][0][ks], a2, 0, 0, 0);
                        a2 = __builtin_amdgcn_mfma_f32_16x16x32_bf16(Ahs[ks], pbl[1][0][ks], a2, 0, 0, 0);
                        a2 = __builtin_amdgcn_mfma_f32_16x16x32_bf16(Ahs[ks], pbh[1][0][ks], a2, 0, 0, 0);
                        a3 = __builtin_amdgcn_mfma_f32_16x16x32_bf16(Ams[ks], pbh[1][1][ks], a3, 0, 0, 0);
                        a3 = __builtin_amdgcn_mfma_f32_16x16x32_bf16(Ahs[ks], pbl[1][1][ks], a3, 0, 0, 0);
                        a3 = __builtin_amdgcn_mfma_f32_16x16x32_bf16(Ahs[ks], pbh[1][1][ks], a3, 0, 0, 0);
                    }
#pragma unroll
                    for (int nt = 0; nt < 2; ++nt) {
                        int e = (2 + nt) * 16 + (lane & 15);
                        const f32x4 a = nt ? a3 : a2;
#pragma unroll
                        for (int r = 0; r < 4; ++r) {
                            int j = wvh * 16 + ((lane >> 4) << 2) + r;
                            scratch[j * 512 + wv8 * 64 + (e ^ (((j >> 2) & 3) << 4))] = a[r];
                        }
                    }
                } else {
                    if (nact) LOAD_PAIR(0, nbin, 0);
                }
                __syncthreads();
                // gather (2 e's per thread)
                {
                    if (c == 0) spReg = gstartPacked[gi];
                    int p0 = (int)((spReg >> (5 * c)) & 31);
                    int p1 = (int)((spReg >> (5 * c + 5)) & 31);
                    for (int p = p0; p < p1; ++p) {
                        unsigned en = glist[gi * 32 + p];
                        int slot = (en >> 5) & 7;
                        int j = en & 31;
                        const float2 y = *(const float2*)
                            &scratch[j * 512 + slot * 64 + (ge ^ (((j >> 2) & 3) << 4))];
                        sreg0 += y.x; sreg1 += y.y;
                    }
                }
                __syncthreads();
                act = nact; bin = nbin;
            }
        }

        // gates B-frags ks0, ks1 issued early (hidden under s-finalize / E_pred)
        s8v gbh[3][4], gbl[3][4];
#pragma unroll
        for (int kp = 0; kp < 2; ++kp)
#pragma unroll
            for (int q = 0; q < 4; ++q) {
                int fo = ((wv8 * 4 + q) * 8 + kp) * 64 + lane;
                gbh[kp][q] = ((const s8v*)W4H)[fo];
                gbl[kp][q] = ((const s8v*)W4L)[fo];
            }

        // finalize s = relu(pooled + bp)
        {
            float v0 = fmaxf(sreg0 + bpL[ge], 0.f);
            float v1 = fmaxf(sreg1 + bpL[ge + 1], 0.f);
            store2(combH, combM, gi * 256 + ((192 + ge)     ^ ((gi & 7) << 3)), v0);
            store2(combH, combM, gi * 256 + ((192 + ge + 1) ^ ((gi & 7) << 3)), v1);
        }

        // ---------- E_pred ----------
        if (t >= OBS_T) {
            if (tid < 256) {
                int i = tid >> 3, d = (tid >> 2) & 1, pp = tid & 3;
                float acc = 0.f;
                int k0 = pp * 32;
                for (int k = k0; k < k0 + 32; ++k)
                    acc += hbuf[i * 128 + (k ^ ((i & 7) << 2))] * WoutL[k * 2 + d];
                red[tid] = acc;
            }
            __syncthreads();
            if (tid < 64) {
                int d = tid & 1;
                float pv = red[tid * 4] + red[tid * 4 + 1] + red[tid * 4 + 2] + red[tid * 4 + 3]
                         + boutL[d];
                out[(t - OBS_T) * 2048 + b * 64 + tid] = pv;
                posb[tid] += pv;
                pvbuf[tid] = pv;
            }
            __syncthreads();
            {
                float x0 = pvbuf[gi * 2], x1 = pvbuf[gi * 2 + 1];
#pragma unroll
                for (int r = 0; r < 2; ++r) {
                    int e = ge + r;
                    float v = x0 * WeL[e] + x1 * WeL[64 + e] + beL[e];
                    store2(combH, combM, gi * 256 + (e ^ ((gi & 7) << 3)), v);
                }
            }
        }
        __syncthreads();

        // gates extra A-frags: ks 0,1,6,7 (ks 2..5 reuse Ahs/Ams)
        s8v gAh[4], gAm[4];
        {
            const int ksmap[4] = {0, 1, 6, 7};
#pragma unroll
            for (int ii = 0; ii < 4; ++ii) {
                int k = ksmap[ii] * 32 + ((lane >> 4) << 3);
                int ci = arow * 256 + (k ^ ((arow & 7) << 3));
                gAh[ii] = *(const s8v*)&combH[ci];
                gAm[ii] = *(const s8v*)&combM[ci];
            }
        }
        // preload ks2 B-frags (depth-3 buffer)
#pragma unroll
        for (int q = 0; q < 4; ++q) {
            int fo = ((wv8 * 4 + q) * 8 + 2) * 64 + lane;
            gbh[2][q] = ((const s8v*)W4H)[fo];
            gbl[2][q] = ((const s8v*)W4L)[fo];
        }

        // ---------- G: gates (bf16x2 MFMA, own row-half) ----------
        {
            f32x4 acc[4];
            f32x4 zero = {0.f, 0.f, 0.f, 0.f};
#pragma unroll
            for (int q = 0; q < 4; ++q) acc[q] = zero;
#pragma unroll
            for (int ks = 0; ks < 8; ++ks) {
                const int cb = ks % 3;
                s8v Ah = (ks < 2) ? gAh[ks] : (ks < 6) ? Ahs[ks - 2] : gAh[ks - 4];
                s8v Am = (ks < 2) ? gAm[ks] : (ks < 6) ? Ams[ks - 2] : gAm[ks - 4];
#pragma unroll
                for (int q = 0; q < 4; ++q) {
                    acc[q] = __builtin_amdgcn_mfma_f32_16x16x32_bf16(Am, gbh[cb][q], acc[q], 0, 0, 0);
                    acc[q] = __builtin_amdgcn_mfma_f32_16x16x32_bf16(Ah, gbl[cb][q], acc[q], 0, 0, 0);
                    acc[q] = __builtin_amdgcn_mfma_f32_16x16x32_bf16(Ah, gbh[cb][q], acc[q], 0, 0, 0);
                }
                if (ks < 5) {
#pragma unroll
                    for (int q = 0; q < 4; ++q) {
                        int fo = ((wv8 * 4 + q) * 8 + ks + 3) * 64 + lane;
                        gbh[cb][q] = ((const s8v*)W4H)[fo];
                        gbl[cb][q] = ((const s8v*)W4L)[fo];
                    }
                }
            }
            __syncthreads();  // all waves done reading comb before h writes

            // in-register cell: 4 (row,hc) per lane
            float b0 = biasL[hc], b1 = biasL[128 + hc], b2 = biasL[256 + hc], b3 = biasL[384 + hc];
#pragma unroll
            for (int r = 0; r < 4; ++r) {
                int row = wvh * 16 + ((lane >> 4) << 2) + r;
                float pi = acc[0][r] + b0;
                float pf = acc[1][r] + b1;
                float po = acc[2][r] + b2;
                float pg = acc[3][r] + b3;
                float ig = 1.f / (1.f + expf(-pi));
                float fg = 1.f / (1.f + expf(-pf));
                float og = 1.f / (1.f + expf(-po));
                float gv = tanhf(pg);
                float cv = fg * creg[r] + ig * gv;
                creg[r] = cv;
                float hv = og * tanhf(cv);
                hbuf[row * 128 + (hc ^ ((row & 7) << 2))] = hv;
                store2(combH, combM, row * 256 + ((64 + hc) ^ ((row & 7) << 3)), hv);
            }
        }
        __syncthreads();
    }
}

extern "C" void kernel_launch(void* const* d_in, const int* in_sizes, int n_in,
                              void* d_out, int out_size, void* d_ws, size_t ws_size,
                              hipStream_t stream) {
    const float* obs_rel = (const float*)d_in[0];
    const float* obs_abs = (const float*)d_in[1];
    // d_in[2]: seq_start_end — fixed contiguous blocks of 32, unused
    const float* We   = (const float*)d_in[3];
    const float* be   = (const float*)d_in[4];
    const float* Wp   = (const float*)d_in[5];
    const float* bp   = (const float*)d_in[6];
    const float* Wi   = (const float*)d_in[7];
    const float* bi   = (const float*)d_in[8];
    const float* Wf   = (const float*)d_in[9];
    const float* bf   = (const float*)d_in[10];
    const float* Wo   = (const float*)d_in[11];
    const float* bo   = (const float*)d_in[12];
    const float* Wg   = (const float*)d_in[13];
    const float* bg   = (const float*)d_in[14];
    const float* Wout = (const float*)d_in[15];
    const float* bout = (const float*)d_in[16];

    unsigned short* ws = (unsigned short*)d_ws;
    unsigned short* W4H = ws;
    unsigned short* W4L = W4H + 131072;
    unsigned short* WpH = W4L + 131072;
    unsigned short* WpL = WpH + 524288;

    slstm_prep<<<2560, 256, 0, stream>>>(Wp, Wi, Wf, Wo, Wg, W4H, W4L, WpH, WpL);
    slstm_main<<<32, 1024, 0, stream>>>(obs_rel, obs_abs, We, be, bp, bi, bf, bo, bg,
                                        Wout, bout, W4H, W4L, WpH, WpL,
                                        (float*)d_out);
}

// Round 9
// 1868.094 us; speedup vs baseline: 1.9362x; 1.9362x over previous
//
#include <hip/hip_runtime.h>

typedef short s8v __attribute__((ext_vector_type(8)));
typedef float f32x4 __attribute__((ext_vector_type(4)));

#define OBS_T 8
#define NSTEPS 20

__device__ __forceinline__ unsigned short f2bf(float x) {
    unsigned u = __float_as_uint(x);
    u = (u + 0x7FFFu + ((u >> 16) & 1u)) >> 16;
    return (unsigned short)u;
}
__device__ __forceinline__ float bf2f(unsigned short h) {
    return __uint_as_float(((unsigned)h) << 16);
}

__device__ __forceinline__ void store2(unsigned short* H, unsigned short* M,
                                       int ci, float v) {
    unsigned short h = f2bf(v);
    H[ci] = h; M[ci] = f2bf(v - bf2f(h));
}

// ---------------- prep: pack x2-split bf16 weight fragments (unchanged) ----------------
__global__ void slstm_prep(const float* __restrict__ Wp,
                           const float* __restrict__ Wi, const float* __restrict__ Wf,
                           const float* __restrict__ Wo, const float* __restrict__ Wg,
                           unsigned short* __restrict__ W4H, unsigned short* __restrict__ W4L,
                           unsigned short* __restrict__ WpH, unsigned short* __restrict__ WpL) {
    int x = blockIdx.x * blockDim.x + threadIdx.x;
    const int NW4 = 32 * 8 * 64 * 8;      // 131072
    const int NWP = 64 * 4 * 4 * 64 * 8;  // 524288
    if (x < NW4) {
        int j = x & 7, lane = (x >> 3) & 63, ks = (x >> 9) & 7, nt2 = x >> 12;
        int q = nt2 & 3, wvb = nt2 >> 2;
        int col = wvb * 16 + (lane & 15);
        int k = ks * 32 + ((lane >> 4) << 3) + j;
        const float* W = (q == 0) ? Wi : (q == 1) ? Wf : (q == 2) ? Wo : Wg;
        float v = W[k * 128 + col];
        unsigned short h = f2bf(v);
        W4H[x] = h; W4L[x] = f2bf(v - bf2f(h));
    } else if (x < NW4 + NWP) {
        int y = x - NW4;
        int j = y & 7, lane = (y >> 3) & 63, ks = (y >> 9) & 3, nt = (y >> 11) & 3, bin = y >> 13;
        int e = nt * 16 + (lane & 15);
        int k = ks * 32 + ((lane >> 4) << 3) + j;
        float v = Wp[(bin * 128 + k) * 64 + e];
        unsigned short h = f2bf(v);
        WpH[y] = h; WpL[y] = f2bf(v - bf2f(h));
    }
}

// ---------------- main persistent kernel: 1 WG (1024 thr, 16 waves) per sequence ----------------
__global__ __launch_bounds__(1024, 4) void slstm_main(
    const float* __restrict__ obs_rel, const float* __restrict__ obs_abs,
    const float* __restrict__ We, const float* __restrict__ be,
    const float* __restrict__ bp,
    const float* __restrict__ bi, const float* __restrict__ bfv,
    const float* __restrict__ bo, const float* __restrict__ bg,
    const float* __restrict__ Wout, const float* __restrict__ bout,
    const unsigned short* __restrict__ W4H, const unsigned short* __restrict__ W4L,
    const unsigned short* __restrict__ WpH, const unsigned short* __restrict__ WpL,
    float* __restrict__ out) {

    __shared__ __align__(16) unsigned short combH[32 * 256];
    __shared__ __align__(16) unsigned short combM[32 * 256];
    __shared__ __align__(16) float hbuf[32 * 128];
    __shared__ __align__(16) float scratch[32 * 512];
    __shared__ float posb[64];
    __shared__ float pvbuf[64];
    __shared__ float red[256];
    __shared__ unsigned char binTab[1024];
    __shared__ unsigned char usedList[64];
    __shared__ unsigned char binSlotG[64];
    __shared__ unsigned short glist[1024];
    __shared__ unsigned long long gstartPacked[32];
    __shared__ int nUsedS;
    __shared__ unsigned usedMask[2];
    __shared__ unsigned jm[4];
    __shared__ float biasL[512], beL[64], bpL[64], WeL[128], WoutL[256], boutL[2];

    const int tid = threadIdx.x;
    const int lane = tid & 63;
    const int wv = tid >> 6;          // 0..15
    const int wv8 = wv & 7;           // bin slot / hcol block
    const int wvh = wv >> 3;          // j-half (social) / row-half (gates)
    const int b = blockIdx.x;

    if (tid < 512) biasL[tid] = (tid < 128) ? bi[tid] : (tid < 256) ? bfv[tid - 128]
                              : (tid < 384) ? bo[tid - 256] : bg[tid - 384];
    if (tid < 64) { beL[tid] = be[tid]; bpL[tid] = bp[tid]; }
    if (tid < 128) WeL[tid] = We[tid];
    if (tid < 256) WoutL[tid] = Wout[tid];
    if (tid < 2) boutL[tid] = bout[tid];
    for (int x = tid; x < 32 * 256; x += 1024) { combH[x] = 0; combM[x] = 0; }
    for (int x = tid; x < 32 * 128; x += 1024) hbuf[x] = 0.f;
    float creg[4];
#pragma unroll
    for (int r = 0; r < 4; ++r) creg[r] = 0.f;
    __syncthreads();

    const float gnorm = (float)(2.0 / 7.0);
    const int gi = tid >> 5;          // ped 0..31 (gather / emb / s-finalize)
    const int ge = (tid & 31) * 2;    // two e's per thread
    const int hc = wv8 * 16 + (lane & 15);        // gate/cell hcol
    const int arow = wvh * 16 + (lane & 15);      // A-frag row (own half)

    for (int t = 0; t < NSTEPS; ++t) {
        // ---------- E_obs ----------
        if (t < OBS_T) {
            if (tid < 64) posb[tid] = obs_abs[t * 2048 + b * 64 + tid];
            {
                float x0 = obs_rel[t * 2048 + b * 64 + gi * 2];
                float x1 = obs_rel[t * 2048 + b * 64 + gi * 2 + 1];
#pragma unroll
                for (int r = 0; r < 2; ++r) {
                    int e = ge + r;
                    float v = x0 * WeL[e] + x1 * WeL[64 + e] + beL[e];
                    store2(combH, combM, gi * 256 + (e ^ ((gi & 7) << 3)), v);
                }
            }
        }
        if (tid < 2) usedMask[tid] = 0u;
        if (tid < 4) jm[tid] = 0u;
        __syncthreads();

        // ---------- S0: bins (one pair per thread) ----------
        if (t > 0) {
            int i = tid >> 5, j = tid & 31;
            float rx = (posb[j * 2]     - posb[i * 2])     / gnorm;
            float ry = (posb[j * 2 + 1] - posb[i * 2 + 1]) / gnorm;
            rx = fminf(fmaxf(rx, -4.f), 4.f);
            ry = fminf(fmaxf(ry, -4.f), 4.f);
            int gx = (int)(rx + 4.f);
            int gy = (int)(ry + 4.f);
            int valid = (gx < 8) && (gy < 8) && (i != j);
            int bin = gy * 8 + gx;
            binTab[tid] = valid ? (unsigned char)bin : (unsigned char)255;
            if (valid) {
                atomicOr(&usedMask[bin >> 5], 1u << (bin & 31));
                atomicOr(&jm[((j < 16) ? 0 : 2) + (bin >> 5)], 1u << (bin & 31));
            }
        }
        __syncthreads();
        // ---------- S1: ballot compaction (wave 0) ----------
        if (t > 0 && wv == 0) {
            bool used = (usedMask[lane >> 5] >> (lane & 31)) & 1u;
            unsigned long long bal = __ballot(used);
            int myIdx = __popcll(bal & ((1ull << lane) - 1ull));
            if (used) usedList[myIdx] = (unsigned char)lane;
            binSlotG[lane] = used ? (unsigned char)myIdx : (unsigned char)255;
            if (lane == 0) nUsedS = __popcll(bal);
        }
        __syncthreads();
        const int nUsed = (t > 0) ? nUsedS : 0;
        const int nChunks = (nUsed + 7) >> 3;

        // A-frags for own row/j half (comb cols 64..191) — also reused by gates ks2..5
        s8v Ahs[4], Ams[4];
#pragma unroll
        for (int ks = 0; ks < 4; ++ks) {
            int k = ks * 32 + ((lane >> 4) << 3);
            int ci = arow * 256 + ((64 + k) ^ ((arow & 7) << 3));
            Ahs[ks] = *(const s8v*)&combH[ci];
            Ams[ks] = *(const s8v*)&combM[ci];
        }

        // glist build (tid<32)
        if (t > 0 && tid < 32) {
            const int i = tid;
            unsigned rw[8];
#pragma unroll
            for (int w = 0; w < 8; ++w)
                rw[w] = *(const unsigned*)&binTab[i * 32 + w * 4];
            unsigned long long cntp = 0;
#pragma unroll
            for (int j = 0; j < 32; ++j) {
                unsigned bb = (rw[j >> 2] >> ((j & 3) * 8)) & 255u;
                if (bb != 255u) cntp += 1ull << (5 * (binSlotG[bb] >> 3));
            }
            unsigned long long pre = 0; unsigned sum = 0;
#pragma unroll
            for (int c = 0; c < 8; ++c) {
                pre |= (unsigned long long)sum << (5 * c);
                sum += (unsigned)((cntp >> (5 * c)) & 31);
            }
            gstartPacked[i] = pre | ((unsigned long long)sum << 40);
            unsigned long long pos = pre;
#pragma unroll
            for (int j = 0; j < 32; ++j) {
                unsigned bb = (rw[j >> 2] >> ((j & 3) * 8)) & 255u;
                if (bb != 255u) {
                    int sg = binSlotG[bb];
                    int c = sg >> 3;
                    int p = (int)((pos >> (5 * c)) & 31);
                    glist[i * 32 + p] = (unsigned short)((sg << 5) | j);
                    pos += 1ull << (5 * c);
                }
            }
        }

        float sreg0 = 0.f, sreg1 = 0.f;
        if (t > 0) {
            unsigned long long spReg = 0;
            for (int c = 0; c < nChunks; ++c) {
                int idx = c * 8 + wv8;
                bool act = false; int bin = 0;
                if (idx < nUsed) {
                    bin = usedList[idx];
                    act = (jm[2 * wvh + (bin >> 5)] >> (bin & 31)) & 1;
                }
                if (act) {
#pragma unroll
                    for (int np = 0; np < 2; ++np) {   // nt pairs {0,1}, {2,3}
                        s8v bh0[4], bl0[4], bh1[4], bl1[4];
#pragma unroll
                        for (int ks = 0; ks < 4; ++ks) {
                            int foA = ((bin * 4 + np * 2)     * 4 + ks) * 64 + lane;
                            int foB = ((bin * 4 + np * 2 + 1) * 4 + ks) * 64 + lane;
                            bh0[ks] = ((const s8v*)WpH)[foA];
                            bl0[ks] = ((const s8v*)WpL)[foA];
                            bh1[ks] = ((const s8v*)WpH)[foB];
                            bl1[ks] = ((const s8v*)WpL)[foB];
                        }
                        f32x4 a0 = {0.f, 0.f, 0.f, 0.f};
                        f32x4 a1 = {0.f, 0.f, 0.f, 0.f};
#pragma unroll
                        for (int ks = 0; ks < 4; ++ks) {
                            a0 = __builtin_amdgcn_mfma_f32_16x16x32_bf16(Ams[ks], bh0[ks], a0, 0, 0, 0);
                            a0 = __builtin_amdgcn_mfma_f32_16x16x32_bf16(Ahs[ks], bl0[ks], a0, 0, 0, 0);
                            a0 = __builtin_amdgcn_mfma_f32_16x16x32_bf16(Ahs[ks], bh0[ks], a0, 0, 0, 0);
                            a1 = __builtin_amdgcn_mfma_f32_16x16x32_bf16(Ams[ks], bh1[ks], a1, 0, 0, 0);
                            a1 = __builtin_amdgcn_mfma_f32_16x16x32_bf16(Ahs[ks], bl1[ks], a1, 0, 0, 0);
                            a1 = __builtin_amdgcn_mfma_f32_16x16x32_bf16(Ahs[ks], bh1[ks], a1, 0, 0, 0);
                        }
#pragma unroll
                        for (int nt = 0; nt < 2; ++nt) {
                            int e = (np * 2 + nt) * 16 + (lane & 15);
                            const f32x4 a = nt ? a1 : a0;
#pragma unroll
                            for (int r = 0; r < 4; ++r) {
                                int j = wvh * 16 + ((lane >> 4) << 2) + r;
                                scratch[j * 512 + wv8 * 64 + (e ^ (((j >> 2) & 3) << 4))] = a[r];
                            }
                        }
                    }
                }
                __syncthreads();
                // gather (2 e's per thread)
                {
                    if (c == 0) spReg = gstartPacked[gi];
                    int p0 = (int)((spReg >> (5 * c)) & 31);
                    int p1 = (int)((spReg >> (5 * c + 5)) & 31);
                    for (int p = p0; p < p1; ++p) {
                        unsigned en = glist[gi * 32 + p];
                        int slot = (en >> 5) & 7;
                        int j = en & 31;
                        const float2 y = *(const float2*)
                            &scratch[j * 512 + slot * 64 + (ge ^ (((j >> 2) & 3) << 4))];
                        sreg0 += y.x; sreg1 += y.y;
                    }
                }
                __syncthreads();
            }
        }

        // finalize s = relu(pooled + bp)
        {
            float v0 = fmaxf(sreg0 + bpL[ge], 0.f);
            float v1 = fmaxf(sreg1 + bpL[ge + 1], 0.f);
            store2(combH, combM, gi * 256 + ((192 + ge)     ^ ((gi & 7) << 3)), v0);
            store2(combH, combM, gi * 256 + ((192 + ge + 1) ^ ((gi & 7) << 3)), v1);
        }

        // ---------- E_pred ----------
        if (t >= OBS_T) {
            if (tid < 256) {
                int i = tid >> 3, d = (tid >> 2) & 1, pp = tid & 3;
                float acc = 0.f;
                int k0 = pp * 32;
                for (int k = k0; k < k0 + 32; ++k)
                    acc += hbuf[i * 128 + (k ^ ((i & 7) << 2))] * WoutL[k * 2 + d];
                red[tid] = acc;
            }
            __syncthreads();
            if (tid < 64) {
                int d = tid & 1;
                float pv = red[tid * 4] + red[tid * 4 + 1] + red[tid * 4 + 2] + red[tid * 4 + 3]
                         + boutL[d];
                out[(t - OBS_T) * 2048 + b * 64 + tid] = pv;
                posb[tid] += pv;
                pvbuf[tid] = pv;
            }
            __syncthreads();
            {
                float x0 = pvbuf[gi * 2], x1 = pvbuf[gi * 2 + 1];
#pragma unroll
                for (int r = 0; r < 2; ++r) {
                    int e = ge + r;
                    float v = x0 * WeL[e] + x1 * WeL[64 + e] + beL[e];
                    store2(combH, combM, gi * 256 + (e ^ ((gi & 7) << 3)), v);
                }
            }
        }
        __syncthreads();

        // gates extra A-frags: ks 0,1,6,7 (ks 2..5 reuse Ahs/Ams)
        s8v gAh[4], gAm[4];
        {
            const int ksmap[4] = {0, 1, 6, 7};
#pragma unroll
            for (int ii = 0; ii < 4; ++ii) {
                int k = ksmap[ii] * 32 + ((lane >> 4) << 3);
                int ci = arow * 256 + (k ^ ((arow & 7) << 3));
                gAh[ii] = *(const s8v*)&combH[ci];
                gAm[ii] = *(const s8v*)&combM[ci];
            }
        }

        // ---------- G: gates (bf16x2 MFMA, own row-half, single-buffered loads) ----------
        {
            f32x4 acc[4];
            f32x4 zero = {0.f, 0.f, 0.f, 0.f};
#pragma unroll
            for (int q = 0; q < 4; ++q) acc[q] = zero;
#pragma unroll
            for (int ks = 0; ks < 8; ++ks) {
                s8v gbh[4], gbl[4];
#pragma unroll
                for (int q = 0; q < 4; ++q) {
                    int fo = ((wv8 * 4 + q) * 8 + ks) * 64 + lane;
                    gbh[q] = ((const s8v*)W4H)[fo];
                    gbl[q] = ((const s8v*)W4L)[fo];
                }
                s8v Ah = (ks < 2) ? gAh[ks] : (ks < 6) ? Ahs[ks - 2] : gAh[ks - 4];
                s8v Am = (ks < 2) ? gAm[ks] : (ks < 6) ? Ams[ks - 2] : gAm[ks - 4];
#pragma unroll
                for (int q = 0; q < 4; ++q) {
                    acc[q] = __builtin_amdgcn_mfma_f32_16x16x32_bf16(Am, gbh[q], acc[q], 0, 0, 0);
                    acc[q] = __builtin_amdgcn_mfma_f32_16x16x32_bf16(Ah, gbl[q], acc[q], 0, 0, 0);
                    acc[q] = __builtin_amdgcn_mfma_f32_16x16x32_bf16(Ah, gbh[q], acc[q], 0, 0, 0);
                }
            }
            __syncthreads();  // all waves done reading comb before h writes

            // in-register cell: 4 (row,hc) per lane
            float b0 = biasL[hc], b1 = biasL[128 + hc], b2 = biasL[256 + hc], b3 = biasL[384 + hc];
#pragma unroll
            for (int r = 0; r < 4; ++r) {
                int row = wvh * 16 + ((lane >> 4) << 2) + r;
                float pi = acc[0][r] + b0;
                float pf = acc[1][r] + b1;
                float po = acc[2][r] + b2;
                float pg = acc[3][r] + b3;
                float ig = 1.f / (1.f + expf(-pi));
                float fg = 1.f / (1.f + expf(-pf));
                float og = 1.f / (1.f + expf(-po));
                float gv = tanhf(pg);
                float cv = fg * creg[r] + ig * gv;
                creg[r] = cv;
                float hv = og * tanhf(cv);
                hbuf[row * 128 + (hc ^ ((row & 7) << 2))] = hv;
                store2(combH, combM, row * 256 + ((64 + hc) ^ ((row & 7) << 3)), hv);
            }
        }
        __syncthreads();
    }
}

extern "C" void kernel_launch(void* const* d_in, const int* in_sizes, int n_in,
                              void* d_out, int out_size, void* d_ws, size_t ws_size,
                              hipStream_t stream) {
    const float* obs_rel = (const float*)d_in[0];
    const float* obs_abs = (const float*)d_in[1];
    // d_in[2]: seq_start_end — fixed contiguous blocks of 32, unused
    const float* We   = (const float*)d_in[3];
    const float* be   = (const float*)d_in[4];
    const float* Wp   = (const float*)d_in[5];
    const float* bp   = (const float*)d_in[6];
    const float* Wi   = (const float*)d_in[7];
    const float* bi   = (const float*)d_in[8];
    const float* Wf   = (const float*)d_in[9];
    const float* bf   = (const float*)d_in[10];
    const float* Wo   = (const float*)d_in[11];
    const float* bo   = (const float*)d_in[12];
    const float* Wg   = (const float*)d_in[13];
    const float* bg   = (const float*)d_in[14];
    const float* Wout = (const float*)d_in[15];
    const float* bout = (const float*)d_in[16];

    unsigned short* ws = (unsigned short*)d_ws;
    unsigned short* W4H = ws;
    unsigned short* W4L = W4H + 131072;
    unsigned short* WpH = W4L + 131072;
    unsigned short* WpL = WpH + 524288;

    slstm_prep<<<2560, 256, 0, stream>>>(Wp, Wi, Wf, Wo, Wg, W4H, W4L, WpH, WpL);
    slstm_main<<<32, 1024, 0, stream>>>(obs_rel, obs_abs, We, be, bp, bi, bf, bo, bg,
                                        Wout, bout, W4H, W4L, WpH, WpL,
                                        (float*)d_out);
}